// Round 13
// baseline (608.060 us; speedup 1.0000x reference)
//
#include <hip/hip_runtime.h>
#include <hip/hip_bf16.h>

typedef unsigned int u32;
typedef unsigned short u16;

using bf16x8 = __attribute__((ext_vector_type(8))) short;
using f32x4  = __attribute__((ext_vector_type(4))) float;
using u16x4e = __attribute__((ext_vector_type(4))) unsigned short;
using u32x4e = __attribute__((ext_vector_type(4))) unsigned int;
using f32x4e = __attribute__((ext_vector_type(4))) float;

#define DEVI static __device__ __forceinline__

DEVI u16 f2bf(float f) {
  __hip_bfloat16 h = __float2bfloat16(f);  // RNE
  union { __hip_bfloat16 h; u16 u; } v; v.h = h;
  return v.u;
}

// ---------------------------------------------------------------------------
// Kernel 1: select + convert x[:, :2048, :] (f32) -> Xb bf16 [8192][2048]
// Router is identity: softmax over size-1 axis == 1.0; top_k of equal scores
// returns indices 0..2047 (stable tie-break). NT store: don't pollute L2.
// ---------------------------------------------------------------------------
__global__ void k_convert_x(const float* __restrict__ x, u16* __restrict__ xb) {
  int idx = blockIdx.x * blockDim.x + threadIdx.x;   // 4 elems per thread
  size_t e = (size_t)idx * 4;
  int row = (int)(e >> 11);        // 0..8191
  int d   = (int)(e & 2047);
  int b = row >> 11, t = row & 2047;
  const float4 v = *reinterpret_cast<const float4*>(
      x + ((size_t)(b * 4096 + t) * 2048 + d));
  u16x4e o;
  o.x = f2bf(v.x); o.y = f2bf(v.y); o.z = f2bf(v.z); o.w = f2bf(v.w);
  __builtin_nontemporal_store(
      o, reinterpret_cast<u16x4e*>(xb + (size_t)row * 2048 + d));
}

// ---------------------------------------------------------------------------
// Kernel 2: transpose + convert  in[R][C] f32  ->  out[C][R] bf16  (NT store)
// ---------------------------------------------------------------------------
__global__ void k_transpose_bf16(const float* __restrict__ in,
                                 u16* __restrict__ out, int R, int C) {
  __shared__ u16 lds[64][66];
  const int t = threadIdx.x;        // 256
  const int tile_r = blockIdx.y * 64;
  const int tile_c = blockIdx.x * 64;
  const int cc = (t & 15) * 4;
  const int r0 = t >> 4;
#pragma unroll
  for (int i = 0; i < 4; ++i) {
    int r = r0 + i * 16;
    const float4 v = *reinterpret_cast<const float4*>(
        in + (size_t)(tile_r + r) * C + tile_c + cc);
    lds[r][cc]     = f2bf(v.x);
    lds[r][cc + 1] = f2bf(v.y);
    lds[r][cc + 2] = f2bf(v.z);
    lds[r][cc + 3] = f2bf(v.w);
  }
  __syncthreads();
  const int rr = (t & 15) * 4;
  const int c0 = t >> 4;
#pragma unroll
  for (int i = 0; i < 4; ++i) {
    int c = c0 + i * 16;
    u16x4e o;
    o.x = lds[rr][c]; o.y = lds[rr + 1][c];
    o.z = lds[rr + 2][c]; o.w = lds[rr + 3][c];
    __builtin_nontemporal_store(
        o, reinterpret_cast<u16x4e*>(out + (size_t)(tile_c + c) * R + tile_r + rr));
  }
}

// ---------------------------------------------------------------------------
// Kernel 3: 256x256 bf16 GEMM (16x16x32), R8 2-barrier overlap schedule
// (best measured). Per K-tile: all 24 ds_reads + 4 stage loads up front;
// q00/q01 gated by compiler counted lgkm; mid-tile lgkmcnt(0)+barrier makes
// buf p restage-safe; counted vmcnt(4) publishes. T2 XOR swizzle (0
// conflicts), T5 setprio, LDS-bounce epilogue with NT stores (keep L2 for
// operand panels — the H/out streams are never re-read by this XCD).
// NOTE: 8-wave blocks cap unified regs at 256/wave (128 VGPR + 128 acc) —
// do not add live fragment state (R9 spill lesson).
// ---------------------------------------------------------------------------
#define GLDS16(g, l)                                                          \
  __builtin_amdgcn_global_load_lds(                                           \
      (const __attribute__((address_space(1))) u32*)(g),                      \
      (__attribute__((address_space(3))) u32*)(l), 16, 0, 0)

template <int DO_GELU, int BNPART>
DEVI void gemm_body(u16* lds, const u16* __restrict__ A,
                    const u16* __restrict__ B, const float* __restrict__ bias,
                    void* __restrict__ Cout, int N, int K, int nbn, int sft) {
  const int bid = blockIdx.x;
  int bm, bn;
  if (BNPART) {
    // XCD owns a bn-panel: per-XCD B working set ~4 MB (L2-resident).
    const int local = bid >> 3;
    bn = ((bid & 7) << sft) + (local & ((1 << sft) - 1));
    bm = local >> sft;
  } else {
    // XCD owns a bm-chunk: per-XCD A working set L2-resident (ffn2).
    const int wg = (bid & 7) * (gridDim.x >> 3) + (bid >> 3);
    bm = wg / nbn; bn = wg % nbn;
  }

  const int tid  = threadIdx.x;
  const int w    = tid >> 6, lane = tid & 63;
  const int wr   = w >> 2, wcol = w & 3;   // wave tile: rows wr*128, cols wcol*64
  const int l15  = lane & 15, lhi = lane >> 4;

  const size_t arow0 = (size_t)bm * 256;
  const size_t brow0 = (size_t)bn * 256;

  // ---- staging: lane covers phys 16B chunk -> logical col chunk is XOR'd
  const int srow  = tid >> 3;                                  // 0..63
  const int scolb = ((tid & 7) * 16) ^ ((srow & 7) << 4);      // byte col in row
  const u16* pA = A + (arow0 + srow) * (size_t)K + (scolb >> 1);
  const u16* pB = B + (brow0 + srow) * (size_t)K + (scolb >> 1);
  const int wA = w * 512;  // u16 offset of this wave's 1KB stage slot

  // ---- fragment-read bases (bytes), swizzle folded in
  const u32 arow_b = (u32)((wr * 128 + l15) * 128);
  const u32 brow_b = (u32)((wcol * 64 + l15) * 128);
  const u32 axor   = (u32)((lhi * 16) ^ ((l15 & 7) << 4));
  const char* ldsb = (const char*)lds;

  f32x4 acc[8][4] = {};
  const int nk = K >> 6;

#define STAGE_PAIR(KT, PB, C)                                                 \
  do {                                                                        \
    GLDS16(pA + (size_t)(KT) * 64 + (size_t)(C) * 64 * (size_t)K,             \
           lds + (PB) * 16384 + (C) * 4096 + wA);                             \
    GLDS16(pB + (size_t)(KT) * 64 + (size_t)(C) * 64 * (size_t)K,             \
           lds + 32768 + (PB) * 16384 + (C) * 4096 + wA);                     \
  } while (0)

#define READ_A(DST, MH, ABASE)                                                \
  _Pragma("unroll") for (int m2 = 0; m2 < 4; ++m2)                            \
  _Pragma("unroll") for (int kk = 0; kk < 2; ++kk)                            \
    DST[m2][kk] = *(const bf16x8*)(ldsb + (ABASE) + arow_b +                  \
                                   ((MH)*4 + m2) * 2048 + (axor ^ (kk << 6)));

#define READ_B(DST, NH, BBASE)                                                \
  _Pragma("unroll") for (int n2 = 0; n2 < 2; ++n2)                            \
  _Pragma("unroll") for (int kk = 0; kk < 2; ++kk)                            \
    DST[n2][kk] = *(const bf16x8*)(ldsb + (BBASE) + brow_b +                  \
                                   ((NH)*2 + n2) * 2048 + (axor ^ (kk << 6)));

#define MFMA_Q(MH, NH, AREG, BREG)                                            \
  _Pragma("unroll") for (int m2 = 0; m2 < 4; ++m2)                            \
  _Pragma("unroll") for (int n2 = 0; n2 < 2; ++n2)                            \
  _Pragma("unroll") for (int kk = 0; kk < 2; ++kk)                            \
    acc[(MH)*4 + m2][(NH)*2 + n2] = __builtin_amdgcn_mfma_f32_16x16x32_bf16(  \
        AREG[m2][kk], BREG[n2][kk], acc[(MH)*4 + m2][(NH)*2 + n2], 0, 0, 0);

  // ---- prologue: kt0 fully staged; kt1 pairs 0,1 in flight.
  STAGE_PAIR(0, 0, 0); STAGE_PAIR(0, 0, 1);
  STAGE_PAIR(0, 0, 2); STAGE_PAIR(0, 0, 3);
  if (nk > 1) {
    STAGE_PAIR(1, 1, 0); STAGE_PAIR(1, 1, 1);
    asm volatile("s_waitcnt vmcnt(4)" ::: "memory");
  } else {
    asm volatile("s_waitcnt vmcnt(0)" ::: "memory");
  }
  __builtin_amdgcn_s_barrier();

  for (int kt = 0; kt < nk; ++kt) {
    const int p = kt & 1;
    const u32 abase = (u32)p * 32768u;            // bytes
    const u32 bbase = 65536u + (u32)p * 32768u;   // bytes
    bf16x8 a0[4][2], a1[4][2], b0[2][2], b1[2][2];

    // issue ALL reads (24) + remaining stage of kt+1 (4), pinned above MFMAs
    READ_A(a0, 0, abase);
    READ_B(b0, 0, bbase);
    READ_B(b1, 1, bbase);
    READ_A(a1, 1, abase);
    if (kt + 1 < nk) { STAGE_PAIR(kt + 1, p ^ 1, 2); STAGE_PAIR(kt + 1, p ^ 1, 3); }
    __builtin_amdgcn_sched_barrier(0);

    // q00/q01: compiler auto-gates on first 12/16 reads; A1 drains underneath
    __builtin_amdgcn_s_setprio(1);
    MFMA_Q(0, 0, a0, b0);
    MFMA_Q(0, 1, a0, b1);
    __builtin_amdgcn_s_setprio(0);

    // all my reads from buf p done; after barrier, every wave's are -> WAR-safe
    asm volatile("s_waitcnt lgkmcnt(0)" ::: "memory");
    __builtin_amdgcn_s_barrier();
    __builtin_amdgcn_sched_barrier(0);
    if (kt + 2 < nk) { STAGE_PAIR(kt + 2, p, 0); STAGE_PAIR(kt + 2, p, 1); }

    __builtin_amdgcn_s_setprio(1);
    MFMA_Q(1, 1, a1, b1);
    MFMA_Q(1, 0, a1, b0);
    __builtin_amdgcn_s_setprio(0);

    // publish p^1: kt+1's 8 loads complete (4 young kt+2 loads stay in flight)
    if (kt + 2 < nk) {
      asm volatile("s_waitcnt vmcnt(4)" ::: "memory");
    } else {
      asm volatile("s_waitcnt vmcnt(0)" ::: "memory");
    }
    __builtin_amdgcn_s_barrier();
  }

  // ---- epilogue: LDS-bounce to coalesced NT stores (main-loop LDS is dead).
  const int colb = (int)brow0 + wcol * 64;
  float bb[4];
#pragma unroll
  for (int n = 0; n < 4; ++n) bb[n] = bias[colb + n * 16 + l15];
  const int tr = lane >> 2, tc = (lane & 3) * 16;

  if (DO_GELU) {
    u16* slot = lds + (size_t)w * 1152;          // 16 x 72 u16
#pragma unroll
    for (int m = 0; m < 8; ++m) {
      const int rowb = (int)arow0 + wr * 128 + m * 16;
#pragma unroll
      for (int n = 0; n < 4; ++n)
#pragma unroll
        for (int r = 0; r < 4; ++r) {
          float v = acc[m][n][r] + bb[n];
          float u2 = v * (1.5957691216f + 0.0713548162f * v * v);
          float g  = v / (1.f + __expf(-u2));
          slot[(lhi * 4 + r) * 72 + n * 16 + l15] = f2bf(g);
        }
      asm volatile("s_waitcnt lgkmcnt(0)" ::: "memory");
      u32x4e d0 = *(const u32x4e*)(slot + tr * 72 + tc);
      u32x4e d1 = *(const u32x4e*)(slot + tr * 72 + tc + 8);
      u16* gp = (u16*)Cout + (size_t)(rowb + tr) * N + colb + tc;
      __builtin_nontemporal_store(d0, (u32x4e*)gp);
      __builtin_nontemporal_store(d1, (u32x4e*)(gp + 8));
      asm volatile("s_waitcnt lgkmcnt(0)" ::: "memory");
    }
  } else {
    float* slotf = (float*)(void*)lds + (size_t)w * 1088;  // 16 x 68 f32
#pragma unroll
    for (int m = 0; m < 8; ++m) {
      const int rowb = (int)arow0 + wr * 128 + m * 16;
#pragma unroll
      for (int n = 0; n < 4; ++n)
#pragma unroll
        for (int r = 0; r < 4; ++r)
          slotf[(lhi * 4 + r) * 68 + n * 16 + l15] = acc[m][n][r] + bb[n];
      asm volatile("s_waitcnt lgkmcnt(0)" ::: "memory");
      f32x4e f0 = *(const f32x4e*)(slotf + tr * 68 + tc);
      f32x4e f1 = *(const f32x4e*)(slotf + tr * 68 + tc + 4);
      f32x4e f2 = *(const f32x4e*)(slotf + tr * 68 + tc + 8);
      f32x4e f3 = *(const f32x4e*)(slotf + tr * 68 + tc + 12);
      float* gp = (float*)Cout + (size_t)(rowb + tr) * N + colb + tc;
      __builtin_nontemporal_store(f0, (f32x4e*)gp);
      __builtin_nontemporal_store(f1, (f32x4e*)(gp + 4));
      __builtin_nontemporal_store(f2, (f32x4e*)(gp + 8));
      __builtin_nontemporal_store(f3, (f32x4e*)(gp + 12));
      asm volatile("s_waitcnt lgkmcnt(0)" ::: "memory");
    }
  }
#undef STAGE_PAIR
#undef READ_A
#undef READ_B
#undef MFMA_Q
}

__global__ __launch_bounds__(512, 2) void k_ffn1(
    const u16* __restrict__ A, const u16* __restrict__ B,
    const float* __restrict__ bias, void* __restrict__ Cout,
    int N, int K, int nbn, int sft) {
  __shared__ __align__(64) u16 lds[65536];
  gemm_body<1, 1>(lds, A, B, bias, Cout, N, K, nbn, sft);
}

__global__ __launch_bounds__(512, 2) void k_ffn2(
    const u16* __restrict__ A, const u16* __restrict__ B,
    const float* __restrict__ bias, void* __restrict__ Cout,
    int N, int K, int nbn, int sft) {
  __shared__ __align__(64) u16 lds[65536];
  gemm_body<0, 0>(lds, A, B, bias, Cout, N, K, nbn, sft);
}

// ---------------------------------------------------------------------------
extern "C" void kernel_launch(void* const* d_in, const int* in_sizes, int n_in,
                              void* d_out, int out_size, void* d_ws,
                              size_t ws_size, hipStream_t stream) {
  const float* x  = (const float*)d_in[0];
  // d_in[1] = Wp, d_in[2] = bp : router is identity, unused.
  const float* W1 = (const float*)d_in[3];
  const float* b1 = (const float*)d_in[4];
  const float* W2 = (const float*)d_in[5];
  const float* b2 = (const float*)d_in[6];
  float* out = (float*)d_out;

  char* ws = (char*)d_ws;
  u16* Xb  = (u16*)(ws);                       // 8192x2048 bf16 = 32 MiB
  u16* W1T = (u16*)(ws + 33554432);            // 8192x2048 bf16 = 32 MiB
  u16* W2T = (u16*)(ws + 67108864);            // 2048x8192 bf16 = 32 MiB
  u16* H   = (u16*)(ws + 100663296);           // 8192x8192 bf16 = 128 MiB

  // 1. select + convert x
  k_convert_x<<<16384, 256, 0, stream>>>(x, Xb);
  // 2. transpose-convert weights
  k_transpose_bf16<<<dim3(8192 / 64, 2048 / 64), 256, 0, stream>>>(W1, W1T, 2048, 8192);
  k_transpose_bf16<<<dim3(2048 / 64, 8192 / 64), 256, 0, stream>>>(W2, W2T, 8192, 2048);
  // 3. H = gelu(Xb @ W1 + b1) : M=8192 N=8192 K=2048, 1024 blocks, bn-panel
  k_ffn1<<<1024, 512, 0, stream>>>(Xb, W1T, b1, (void*)H, 8192, 2048, 32, 2);
  // 4. out = H @ W2 + b2      : M=8192 N=2048 K=8192, 256 blocks, bm-chunk
  k_ffn2<<<256, 512, 0, stream>>>(H, W2T, b2, (void*)out, 2048, 8192, 8, 0);
}

// Round 14
// 541.158 us; speedup vs baseline: 1.1236x; 1.1236x over previous
//
#include <hip/hip_runtime.h>
#include <hip/hip_bf16.h>

typedef unsigned int u32;
typedef unsigned short u16;

using bf16x8 = __attribute__((ext_vector_type(8))) short;
using f32x4  = __attribute__((ext_vector_type(4))) float;
using u16x4e = __attribute__((ext_vector_type(4))) unsigned short;
using u32x4e = __attribute__((ext_vector_type(4))) unsigned int;
using f32x4e = __attribute__((ext_vector_type(4))) float;

#define DEVI static __device__ __forceinline__

DEVI u16 f2bf(float f) {
  __hip_bfloat16 h = __float2bfloat16(f);  // RNE
  union { __hip_bfloat16 h; u16 u; } v; v.h = h;
  return v.u;
}

// ---------------------------------------------------------------------------
// Kernel 1: select + convert x[:, :2048, :] (f32) -> Xb bf16 [8192][2048]
// Router is identity: softmax over size-1 axis == 1.0; top_k of equal scores
// returns indices 0..2047 (stable tie-break). NT store (no L2 pollution).
// ---------------------------------------------------------------------------
__global__ void k_convert_x(const float* __restrict__ x, u16* __restrict__ xb) {
  int idx = blockIdx.x * blockDim.x + threadIdx.x;   // 4 elems per thread
  size_t e = (size_t)idx * 4;
  int row = (int)(e >> 11);        // 0..8191
  int d   = (int)(e & 2047);
  int b = row >> 11, t = row & 2047;
  const float4 v = *reinterpret_cast<const float4*>(
      x + ((size_t)(b * 4096 + t) * 2048 + d));
  u16x4e o;
  o.x = f2bf(v.x); o.y = f2bf(v.y); o.z = f2bf(v.z); o.w = f2bf(v.w);
  __builtin_nontemporal_store(
      o, reinterpret_cast<u16x4e*>(xb + (size_t)row * 2048 + d));
}

// ---------------------------------------------------------------------------
// Kernel 2: transpose + convert  in[R][C] f32  ->  out[C][R] bf16  (NT store)
// ---------------------------------------------------------------------------
__global__ void k_transpose_bf16(const float* __restrict__ in,
                                 u16* __restrict__ out, int R, int C) {
  __shared__ u16 lds[64][66];
  const int t = threadIdx.x;        // 256
  const int tile_r = blockIdx.y * 64;
  const int tile_c = blockIdx.x * 64;
  const int cc = (t & 15) * 4;
  const int r0 = t >> 4;
#pragma unroll
  for (int i = 0; i < 4; ++i) {
    int r = r0 + i * 16;
    const float4 v = *reinterpret_cast<const float4*>(
        in + (size_t)(tile_r + r) * C + tile_c + cc);
    lds[r][cc]     = f2bf(v.x);
    lds[r][cc + 1] = f2bf(v.y);
    lds[r][cc + 2] = f2bf(v.z);
    lds[r][cc + 3] = f2bf(v.w);
  }
  __syncthreads();
  const int rr = (t & 15) * 4;
  const int c0 = t >> 4;
#pragma unroll
  for (int i = 0; i < 4; ++i) {
    int c = c0 + i * 16;
    u16x4e o;
    o.x = lds[rr][c]; o.y = lds[rr + 1][c];
    o.z = lds[rr + 2][c]; o.w = lds[rr + 3][c];
    __builtin_nontemporal_store(
        o, reinterpret_cast<u16x4e*>(out + (size_t)(tile_c + c) * R + tile_r + rr));
  }
}

// ---------------------------------------------------------------------------
// Kernel 3: 256x256 bf16 GEMM (16x16x32), R8 2-barrier overlap schedule.
// ffn1 (DO_GELU=1): NT stores for H — measured −54 us (own-write L2
// pollution removed). ffn2 (DO_GELU=0): NORMAL stores — R13's NT f32 stores
// caused 2.65x HBM write amplification (170 MB for 64 MB output, +131 us).
// T2 XOR swizzle (0 conflicts), T5 setprio, LDS-bounce epilogue.
// NOTE: 8-wave blocks cap unified regs at 256/wave — no extra live frags.
// ---------------------------------------------------------------------------
#define GLDS16(g, l)                                                          \
  __builtin_amdgcn_global_load_lds(                                           \
      (const __attribute__((address_space(1))) u32*)(g),                      \
      (__attribute__((address_space(3))) u32*)(l), 16, 0, 0)

template <int DO_GELU, int BNPART>
DEVI void gemm_body(u16* lds, const u16* __restrict__ A,
                    const u16* __restrict__ B, const float* __restrict__ bias,
                    void* __restrict__ Cout, int N, int K, int nbn, int sft) {
  const int bid = blockIdx.x;
  int bm, bn;
  if (BNPART) {
    // XCD owns a bn-panel: per-XCD B working set ~4 MB (L2-resident).
    const int local = bid >> 3;
    bn = ((bid & 7) << sft) + (local & ((1 << sft) - 1));
    bm = local >> sft;
  } else {
    // XCD owns a bm-chunk: per-XCD A working set L2-resident (ffn2).
    const int wg = (bid & 7) * (gridDim.x >> 3) + (bid >> 3);
    bm = wg / nbn; bn = wg % nbn;
  }

  const int tid  = threadIdx.x;
  const int w    = tid >> 6, lane = tid & 63;
  const int wr   = w >> 2, wcol = w & 3;   // wave tile: rows wr*128, cols wcol*64
  const int l15  = lane & 15, lhi = lane >> 4;

  const size_t arow0 = (size_t)bm * 256;
  const size_t brow0 = (size_t)bn * 256;

  // ---- staging: lane covers phys 16B chunk -> logical col chunk is XOR'd
  const int srow  = tid >> 3;                                  // 0..63
  const int scolb = ((tid & 7) * 16) ^ ((srow & 7) << 4);      // byte col in row
  const u16* pA = A + (arow0 + srow) * (size_t)K + (scolb >> 1);
  const u16* pB = B + (brow0 + srow) * (size_t)K + (scolb >> 1);
  const int wA = w * 512;  // u16 offset of this wave's 1KB stage slot

  // ---- fragment-read bases (bytes), swizzle folded in
  const u32 arow_b = (u32)((wr * 128 + l15) * 128);
  const u32 brow_b = (u32)((wcol * 64 + l15) * 128);
  const u32 axor   = (u32)((lhi * 16) ^ ((l15 & 7) << 4));
  const char* ldsb = (const char*)lds;

  f32x4 acc[8][4] = {};
  const int nk = K >> 6;

#define STAGE_PAIR(KT, PB, C)                                                 \
  do {                                                                        \
    GLDS16(pA + (size_t)(KT) * 64 + (size_t)(C) * 64 * (size_t)K,             \
           lds + (PB) * 16384 + (C) * 4096 + wA);                             \
    GLDS16(pB + (size_t)(KT) * 64 + (size_t)(C) * 64 * (size_t)K,             \
           lds + 32768 + (PB) * 16384 + (C) * 4096 + wA);                     \
  } while (0)

#define READ_A(DST, MH, ABASE)                                                \
  _Pragma("unroll") for (int m2 = 0; m2 < 4; ++m2)                            \
  _Pragma("unroll") for (int kk = 0; kk < 2; ++kk)                            \
    DST[m2][kk] = *(const bf16x8*)(ldsb + (ABASE) + arow_b +                  \
                                   ((MH)*4 + m2) * 2048 + (axor ^ (kk << 6)));

#define READ_B(DST, NH, BBASE)                                                \
  _Pragma("unroll") for (int n2 = 0; n2 < 2; ++n2)                            \
  _Pragma("unroll") for (int kk = 0; kk < 2; ++kk)                            \
    DST[n2][kk] = *(const bf16x8*)(ldsb + (BBASE) + brow_b +                  \
                                   ((NH)*2 + n2) * 2048 + (axor ^ (kk << 6)));

#define MFMA_Q(MH, NH, AREG, BREG)                                            \
  _Pragma("unroll") for (int m2 = 0; m2 < 4; ++m2)                            \
  _Pragma("unroll") for (int n2 = 0; n2 < 2; ++n2)                            \
  _Pragma("unroll") for (int kk = 0; kk < 2; ++kk)                            \
    acc[(MH)*4 + m2][(NH)*2 + n2] = __builtin_amdgcn_mfma_f32_16x16x32_bf16(  \
        AREG[m2][kk], BREG[n2][kk], acc[(MH)*4 + m2][(NH)*2 + n2], 0, 0, 0);

  // ---- prologue: kt0 fully staged; kt1 pairs 0,1 in flight.
  STAGE_PAIR(0, 0, 0); STAGE_PAIR(0, 0, 1);
  STAGE_PAIR(0, 0, 2); STAGE_PAIR(0, 0, 3);
  if (nk > 1) {
    STAGE_PAIR(1, 1, 0); STAGE_PAIR(1, 1, 1);
    asm volatile("s_waitcnt vmcnt(4)" ::: "memory");
  } else {
    asm volatile("s_waitcnt vmcnt(0)" ::: "memory");
  }
  __builtin_amdgcn_s_barrier();

  for (int kt = 0; kt < nk; ++kt) {
    const int p = kt & 1;
    const u32 abase = (u32)p * 32768u;            // bytes
    const u32 bbase = 65536u + (u32)p * 32768u;   // bytes
    bf16x8 a0[4][2], a1[4][2], b0[2][2], b1[2][2];

    // issue ALL reads (24) + remaining stage of kt+1 (4), pinned above MFMAs
    READ_A(a0, 0, abase);
    READ_B(b0, 0, bbase);
    READ_B(b1, 1, bbase);
    READ_A(a1, 1, abase);
    if (kt + 1 < nk) { STAGE_PAIR(kt + 1, p ^ 1, 2); STAGE_PAIR(kt + 1, p ^ 1, 3); }
    __builtin_amdgcn_sched_barrier(0);

    // q00/q01: compiler auto-gates on first 12/16 reads; A1 drains underneath
    __builtin_amdgcn_s_setprio(1);
    MFMA_Q(0, 0, a0, b0);
    MFMA_Q(0, 1, a0, b1);
    __builtin_amdgcn_s_setprio(0);

    // all my reads from buf p done; after barrier, every wave's are -> WAR-safe
    asm volatile("s_waitcnt lgkmcnt(0)" ::: "memory");
    __builtin_amdgcn_s_barrier();
    __builtin_amdgcn_sched_barrier(0);
    if (kt + 2 < nk) { STAGE_PAIR(kt + 2, p, 0); STAGE_PAIR(kt + 2, p, 1); }

    __builtin_amdgcn_s_setprio(1);
    MFMA_Q(1, 1, a1, b1);
    MFMA_Q(1, 0, a1, b0);
    __builtin_amdgcn_s_setprio(0);

    // publish p^1: kt+1's 8 loads complete (4 young kt+2 loads stay in flight)
    if (kt + 2 < nk) {
      asm volatile("s_waitcnt vmcnt(4)" ::: "memory");
    } else {
      asm volatile("s_waitcnt vmcnt(0)" ::: "memory");
    }
    __builtin_amdgcn_s_barrier();
  }

  // ---- epilogue: LDS-bounce to coalesced stores (main-loop LDS is dead).
  const int colb = (int)brow0 + wcol * 64;
  float bb[4];
#pragma unroll
  for (int n = 0; n < 4; ++n) bb[n] = bias[colb + n * 16 + l15];
  const int tr = lane >> 2, tc = (lane & 3) * 16;

  if (DO_GELU) {
    u16* slot = lds + (size_t)w * 1152;          // 16 x 72 u16
#pragma unroll
    for (int m = 0; m < 8; ++m) {
      const int rowb = (int)arow0 + wr * 128 + m * 16;
#pragma unroll
      for (int n = 0; n < 4; ++n)
#pragma unroll
        for (int r = 0; r < 4; ++r) {
          float v = acc[m][n][r] + bb[n];
          float u2 = v * (1.5957691216f + 0.0713548162f * v * v);
          float g  = v / (1.f + __expf(-u2));
          slot[(lhi * 4 + r) * 72 + n * 16 + l15] = f2bf(g);
        }
      asm volatile("s_waitcnt lgkmcnt(0)" ::: "memory");
      u32x4e d0 = *(const u32x4e*)(slot + tr * 72 + tc);
      u32x4e d1 = *(const u32x4e*)(slot + tr * 72 + tc + 8);
      u16* gp = (u16*)Cout + (size_t)(rowb + tr) * N + colb + tc;
      __builtin_nontemporal_store(d0, (u32x4e*)gp);
      __builtin_nontemporal_store(d1, (u32x4e*)(gp + 8));
      asm volatile("s_waitcnt lgkmcnt(0)" ::: "memory");
    }
  } else {
    float* slotf = (float*)(void*)lds + (size_t)w * 1088;  // 16 x 68 f32
#pragma unroll
    for (int m = 0; m < 8; ++m) {
      const int rowb = (int)arow0 + wr * 128 + m * 16;
#pragma unroll
      for (int n = 0; n < 4; ++n)
#pragma unroll
        for (int r = 0; r < 4; ++r)
          slotf[(lhi * 4 + r) * 68 + n * 16 + l15] = acc[m][n][r] + bb[n];
      asm volatile("s_waitcnt lgkmcnt(0)" ::: "memory");
      float4 f0 = *(const float4*)(slotf + tr * 68 + tc);
      float4 f1 = *(const float4*)(slotf + tr * 68 + tc + 4);
      float4 f2 = *(const float4*)(slotf + tr * 68 + tc + 8);
      float4 f3 = *(const float4*)(slotf + tr * 68 + tc + 12);
      float* gp = (float*)Cout + (size_t)(rowb + tr) * N + colb + tc;
      *(float4*)gp = f0;
      *(float4*)(gp + 4) = f1;
      *(float4*)(gp + 8) = f2;
      *(float4*)(gp + 12) = f3;
      asm volatile("s_waitcnt lgkmcnt(0)" ::: "memory");
    }
  }
#undef STAGE_PAIR
#undef READ_A
#undef READ_B
#undef MFMA_Q
}

__global__ __launch_bounds__(512, 2) void k_ffn1(
    const u16* __restrict__ A, const u16* __restrict__ B,
    const float* __restrict__ bias, void* __restrict__ Cout,
    int N, int K, int nbn, int sft) {
  __shared__ __align__(64) u16 lds[65536];
  gemm_body<1, 1>(lds, A, B, bias, Cout, N, K, nbn, sft);
}

__global__ __launch_bounds__(512, 2) void k_ffn2(
    const u16* __restrict__ A, const u16* __restrict__ B,
    const float* __restrict__ bias, void* __restrict__ Cout,
    int N, int K, int nbn, int sft) {
  __shared__ __align__(64) u16 lds[65536];
  gemm_body<0, 0>(lds, A, B, bias, Cout, N, K, nbn, sft);
}

// ---------------------------------------------------------------------------
extern "C" void kernel_launch(void* const* d_in, const int* in_sizes, int n_in,
                              void* d_out, int out_size, void* d_ws,
                              size_t ws_size, hipStream_t stream) {
  const float* x  = (const float*)d_in[0];
  // d_in[1] = Wp, d_in[2] = bp : router is identity, unused.
  const float* W1 = (const float*)d_in[3];
  const float* b1 = (const float*)d_in[4];
  const float* W2 = (const float*)d_in[5];
  const float* b2 = (const float*)d_in[6];
  float* out = (float*)d_out;

  char* ws = (char*)d_ws;
  u16* Xb  = (u16*)(ws);                       // 8192x2048 bf16 = 32 MiB
  u16* W1T = (u16*)(ws + 33554432);            // 8192x2048 bf16 = 32 MiB
  u16* W2T = (u16*)(ws + 67108864);            // 2048x8192 bf16 = 32 MiB
  u16* H   = (u16*)(ws + 100663296);           // 8192x8192 bf16 = 128 MiB

  // 1. select + convert x
  k_convert_x<<<16384, 256, 0, stream>>>(x, Xb);
  // 2. transpose-convert weights
  k_transpose_bf16<<<dim3(8192 / 64, 2048 / 64), 256, 0, stream>>>(W1, W1T, 2048, 8192);
  k_transpose_bf16<<<dim3(2048 / 64, 8192 / 64), 256, 0, stream>>>(W2, W2T, 8192, 2048);
  // 3. H = gelu(Xb @ W1 + b1) : M=8192 N=8192 K=2048, 1024 blocks, bn-panel
  k_ffn1<<<1024, 512, 0, stream>>>(Xb, W1T, b1, (void*)H, 8192, 2048, 32, 2);
  // 4. out = H @ W2 + b2      : M=8192 N=2048 K=8192, 256 blocks, bm-chunk
  k_ffn2<<<256, 512, 0, stream>>>(H, W2T, b2, (void*)out, 2048, 8192, 8, 0);
}

// Round 15
// 529.472 us; speedup vs baseline: 1.1484x; 1.0221x over previous
//
#include <hip/hip_runtime.h>
#include <hip/hip_bf16.h>

typedef unsigned int u32;
typedef unsigned short u16;

using bf16x8 = __attribute__((ext_vector_type(8))) short;
using f32x4  = __attribute__((ext_vector_type(4))) float;

#define DEVI static __device__ __forceinline__

DEVI u16 f2bf(float f) {
  __hip_bfloat16 h = __float2bfloat16(f);  // RNE
  union { __hip_bfloat16 h; u16 u; } v; v.h = h;
  return v.u;
}

// ---------------------------------------------------------------------------
// Kernel 1: select + convert x[:, :2048, :] (f32) -> Xb bf16 [8192][2048]
// Router is identity: softmax over size-1 axis == 1.0; top_k of equal scores
// returns indices 0..2047 (stable tie-break).
// ---------------------------------------------------------------------------
__global__ void k_convert_x(const float* __restrict__ x, u16* __restrict__ xb) {
  int idx = blockIdx.x * blockDim.x + threadIdx.x;   // 4 elems per thread
  size_t e = (size_t)idx * 4;
  int row = (int)(e >> 11);        // 0..8191
  int d   = (int)(e & 2047);
  int b = row >> 11, t = row & 2047;
  const float4 v = *reinterpret_cast<const float4*>(
      x + ((size_t)(b * 4096 + t) * 2048 + d));
  ushort4 o;
  o.x = f2bf(v.x); o.y = f2bf(v.y); o.z = f2bf(v.z); o.w = f2bf(v.w);
  *reinterpret_cast<ushort4*>(xb + (size_t)row * 2048 + d) = o;
}

// ---------------------------------------------------------------------------
// Kernel 2: transpose + convert  in[R][C] f32  ->  out[C][R] bf16
// ---------------------------------------------------------------------------
__global__ void k_transpose_bf16(const float* __restrict__ in,
                                 u16* __restrict__ out, int R, int C) {
  __shared__ u16 lds[64][66];
  const int t = threadIdx.x;        // 256
  const int tile_r = blockIdx.y * 64;
  const int tile_c = blockIdx.x * 64;
  const int cc = (t & 15) * 4;
  const int r0 = t >> 4;
#pragma unroll
  for (int i = 0; i < 4; ++i) {
    int r = r0 + i * 16;
    const float4 v = *reinterpret_cast<const float4*>(
        in + (size_t)(tile_r + r) * C + tile_c + cc);
    lds[r][cc]     = f2bf(v.x);
    lds[r][cc + 1] = f2bf(v.y);
    lds[r][cc + 2] = f2bf(v.z);
    lds[r][cc + 3] = f2bf(v.w);
  }
  __syncthreads();
  const int rr = (t & 15) * 4;
  const int c0 = t >> 4;
#pragma unroll
  for (int i = 0; i < 4; ++i) {
    int c = c0 + i * 16;
    ushort4 o;
    o.x = lds[rr][c]; o.y = lds[rr + 1][c];
    o.z = lds[rr + 2][c]; o.w = lds[rr + 3][c];
    *reinterpret_cast<ushort4*>(out + (size_t)(tile_c + c) * R + tile_r + rr) = o;
  }
}

// ---------------------------------------------------------------------------
// Shared GEMM machinery (R8-proven 2-barrier overlap k-loop body).
// T2 XOR swizzle (0 conflicts), T5 setprio, counted vmcnt(4).
// NOTE: 8-wave blocks cap unified regs at 256/wave (128 VGPR + 128 acc) —
// do not add live fragment state (R9 spill lesson).
// ---------------------------------------------------------------------------
#define GLDS16(g, l)                                                          \
  __builtin_amdgcn_global_load_lds(                                           \
      (const __attribute__((address_space(1))) u32*)(g),                      \
      (__attribute__((address_space(3))) u32*)(l), 16, 0, 0)

DEVI void stage_pair(u16* lds, const u16* pA, const u16* pB, int lda, int ldb,
                     int kt, int pb, int c, int wA) {
  GLDS16(pA + (size_t)kt * 64 + (size_t)c * 64 * (size_t)lda,
         lds + pb * 16384 + c * 4096 + wA);
  GLDS16(pB + (size_t)kt * 64 + (size_t)c * 64 * (size_t)ldb,
         lds + 32768 + pb * 16384 + c * 4096 + wA);
}

#define READ_A(DST, MH, ABASE)                                                \
  _Pragma("unroll") for (int m2 = 0; m2 < 4; ++m2)                            \
  _Pragma("unroll") for (int kk = 0; kk < 2; ++kk)                            \
    DST[m2][kk] = *(const bf16x8*)(ldsb + (ABASE) + arow_b +                  \
                                   ((MH)*4 + m2) * 2048 + (axor ^ (kk << 6)));

#define READ_B(DST, NH, BBASE)                                                \
  _Pragma("unroll") for (int n2 = 0; n2 < 2; ++n2)                            \
  _Pragma("unroll") for (int kk = 0; kk < 2; ++kk)                            \
    DST[n2][kk] = *(const bf16x8*)(ldsb + (BBASE) + brow_b +                  \
                                   ((NH)*2 + n2) * 2048 + (axor ^ (kk << 6)));

#define MFMA_Q(MH, NH, AREG, BREG)                                            \
  _Pragma("unroll") for (int m2 = 0; m2 < 4; ++m2)                            \
  _Pragma("unroll") for (int n2 = 0; n2 < 2; ++n2)                            \
  _Pragma("unroll") for (int kk = 0; kk < 2; ++kk)                            \
    acc[(MH)*4 + m2][(NH)*2 + n2] = __builtin_amdgcn_mfma_f32_16x16x32_bf16(  \
        AREG[m2][kk], BREG[n2][kk], acc[(MH)*4 + m2][(NH)*2 + n2], 0, 0, 0);

// ---------------------------------------------------------------------------
// k_ffn1: PERSISTENT generations with seamless cross-gen load pipeline.
// Grid 256 (1 block/CU). Block keeps R8's bn-panel (per-XCD B = 4 MB,
// L2-resident all dispatch); sweeps bm = (cu>>2) + 8g over g=0..3.
// The k-loop's staging targets wrap into gen g+1's A-panel (same pB!),
// so every publish is warm: no per-generation prologue bubble, and the
// epilogue overlaps the next generation's in-flight loads.
// Epilogue bounce lives in a DEDICATED LDS region at +65536 u16 (total
// 146 KB < 160 KB; occupancy unchanged at 1 block/CU).
// ---------------------------------------------------------------------------
__global__ __launch_bounds__(512, 2) void k_ffn1(
    const u16* __restrict__ A, const u16* __restrict__ B,
    const float* __restrict__ bias, u16* __restrict__ Cout,
    int N, int K) {
  __shared__ __align__(64) u16 lds[74752];  // 128 KB buffers + 18 KB bounce

  const int bid = blockIdx.x;           // 256
  const int xcd = bid & 7, cu = bid >> 3;
  const int bn    = (xcd << 2) + (cu & 3);   // fixed per block (L2-pinned B)
  const int bmrow = cu >> 2;                 // bm = bmrow + 8*g

  const int tid  = threadIdx.x;
  const int w    = tid >> 6, lane = tid & 63;
  const int wr   = w >> 2, wcol = w & 3;
  const int l15  = lane & 15, lhi = lane >> 4;

  const size_t brow0 = (size_t)bn * 256;
  const int srow  = tid >> 3;
  const int scolb = ((tid & 7) * 16) ^ ((srow & 7) << 4);
  const size_t aoff = (size_t)srow * K + (scolb >> 1);
  const u16* pB = B + (brow0 + srow) * (size_t)K + (scolb >> 1);
  const int wA = w * 512;

  const u32 arow_b = (u32)((wr * 128 + l15) * 128);
  const u32 brow_b = (u32)((wcol * 64 + l15) * 128);
  const u32 axor   = (u32)((lhi * 16) ^ ((l15 & 7) << 4));
  const char* ldsb = (const char*)lds;
  const int nk = K >> 6;   // 32

  u16* slot = lds + 65536 + (size_t)w * 1152;  // dedicated bounce region
  const int tr = lane >> 2, tc = (lane & 3) * 16;

  // ---- one-time prologue (gen 0): tile0 full + tile1 pairs 0,1.
  {
    const u16* pA0 = A + (size_t)bmrow * 256 * K + aoff;
    stage_pair(lds, pA0, pB, K, K, 0, 0, 0, wA);
    stage_pair(lds, pA0, pB, K, K, 0, 0, 1, wA);
    stage_pair(lds, pA0, pB, K, K, 0, 0, 2, wA);
    stage_pair(lds, pA0, pB, K, K, 0, 0, 3, wA);
    stage_pair(lds, pA0, pB, K, K, 1, 1, 0, wA);
    stage_pair(lds, pA0, pB, K, K, 1, 1, 1, wA);
    asm volatile("s_waitcnt vmcnt(4)" ::: "memory");
    __builtin_amdgcn_s_barrier();
  }

  for (int g = 0; g < 4; ++g) {
    const u16* pAc = A + (size_t)(bmrow + 8 * g) * 256 * K + aoff;
    const u16* pAn = A + (size_t)(bmrow + 8 * (g + 1)) * 256 * K + aoff;
    const bool hasNext = (g < 3);

    f32x4 acc[8][4] = {};

    for (int kt = 0; kt < nk; ++kt) {
      const int p = kt & 1;   // global parity == kt&1 (nk even)
      const u32 abase = (u32)p * 32768u;
      const u32 bbase = 65536u + (u32)p * 32768u;
      bf16x8 a0[4][2], a1[4][2], b0[2][2], b1[2][2];

      READ_A(a0, 0, abase);
      READ_B(b0, 0, bbase);
      READ_B(b1, 1, bbase);
      READ_A(a1, 1, abase);
      // stage tile kt+1 pairs 2,3 (wraps into next gen's tile kt+1-32)
      {
        const int t1 = kt + 1;
        if (t1 < nk) {
          stage_pair(lds, pAc, pB, K, K, t1, p ^ 1, 2, wA);
          stage_pair(lds, pAc, pB, K, K, t1, p ^ 1, 3, wA);
        } else if (hasNext) {
          stage_pair(lds, pAn, pB, K, K, t1 - nk, p ^ 1, 2, wA);
          stage_pair(lds, pAn, pB, K, K, t1 - nk, p ^ 1, 3, wA);
        }
      }
      __builtin_amdgcn_sched_barrier(0);

      __builtin_amdgcn_s_setprio(1);
      MFMA_Q(0, 0, a0, b0);
      MFMA_Q(0, 1, a0, b1);
      __builtin_amdgcn_s_setprio(0);

      asm volatile("s_waitcnt lgkmcnt(0)" ::: "memory");
      __builtin_amdgcn_s_barrier();          // buf p restage-safe
      __builtin_amdgcn_sched_barrier(0);
      // stage tile kt+2 pairs 0,1 (wraps into next gen)
      bool staged2 = false;
      {
        const int t2 = kt + 2;
        if (t2 < nk) {
          stage_pair(lds, pAc, pB, K, K, t2, p, 0, wA);
          stage_pair(lds, pAc, pB, K, K, t2, p, 1, wA);
          staged2 = true;
        } else if (hasNext) {
          stage_pair(lds, pAn, pB, K, K, t2 - nk, p, 0, wA);
          stage_pair(lds, pAn, pB, K, K, t2 - nk, p, 1, wA);
          staged2 = true;
        }
      }

      __builtin_amdgcn_s_setprio(1);
      MFMA_Q(1, 1, a1, b1);
      MFMA_Q(1, 0, a1, b0);
      __builtin_amdgcn_s_setprio(0);

      // publish p^1: tile kt+1's 8 loads complete (4 youngest stay in flight)
      if (staged2) {
        asm volatile("s_waitcnt vmcnt(4)" ::: "memory");
      } else {
        asm volatile("s_waitcnt vmcnt(0)" ::: "memory");
      }
      __builtin_amdgcn_s_barrier();
    }

    // ---- epilogue: gelu + dedicated-LDS bounce + coalesced bf16 stores.
    // Runs while next gen's tile0/tile1 loads sit published/in flight in
    // the main buffers (bounce region is disjoint).
    const int arow0 = (bmrow + 8 * g) * 256;
    const int colb  = (int)brow0 + wcol * 64;
    float bb[4];
#pragma unroll
    for (int n = 0; n < 4; ++n) bb[n] = bias[colb + n * 16 + l15];
#pragma unroll
    for (int m = 0; m < 8; ++m) {
      const int rowb = arow0 + wr * 128 + m * 16;
#pragma unroll
      for (int n = 0; n < 4; ++n)
#pragma unroll
        for (int r = 0; r < 4; ++r) {
          float v = acc[m][n][r] + bb[n];
          float u2 = v * (1.5957691216f + 0.0713548162f * v * v);
          float gl = v / (1.f + __expf(-u2));
          slot[(lhi * 4 + r) * 72 + n * 16 + l15] = f2bf(gl);
        }
      asm volatile("s_waitcnt lgkmcnt(0)" ::: "memory");
      uint4 d0 = *(const uint4*)(slot + tr * 72 + tc);
      uint4 d1 = *(const uint4*)(slot + tr * 72 + tc + 8);
      u16* gp = Cout + (size_t)(rowb + tr) * N + colb + tc;
      *(uint4*)gp = d0;
      *(uint4*)(gp + 8) = d1;
      asm volatile("s_waitcnt lgkmcnt(0)" ::: "memory");
    }
  }
}

// ---------------------------------------------------------------------------
// k_ffn2: exact R8 (single tile per block, bm-chunk XCD swizzle, f32 out).
// ---------------------------------------------------------------------------
__global__ __launch_bounds__(512, 2) void k_ffn2(
    const u16* __restrict__ A, const u16* __restrict__ B,
    const float* __restrict__ bias, float* __restrict__ Cout,
    int N, int K, int nbn) {
  __shared__ __align__(64) u16 lds[65536];

  const int bid = blockIdx.x;
  const int wg  = (bid & 7) * (gridDim.x >> 3) + (bid >> 3);
  const int bm = wg / nbn, bn = wg % nbn;

  const int tid  = threadIdx.x;
  const int w    = tid >> 6, lane = tid & 63;
  const int wr   = w >> 2, wcol = w & 3;
  const int l15  = lane & 15, lhi = lane >> 4;

  const size_t arow0 = (size_t)bm * 256;
  const size_t brow0 = (size_t)bn * 256;
  const int srow  = tid >> 3;
  const int scolb = ((tid & 7) * 16) ^ ((srow & 7) << 4);
  const u16* pA = A + (arow0 + srow) * (size_t)K + (scolb >> 1);
  const u16* pB = B + (brow0 + srow) * (size_t)K + (scolb >> 1);
  const int wA = w * 512;

  const u32 arow_b = (u32)((wr * 128 + l15) * 128);
  const u32 brow_b = (u32)((wcol * 64 + l15) * 128);
  const u32 axor   = (u32)((lhi * 16) ^ ((l15 & 7) << 4));
  const char* ldsb = (const char*)lds;
  const int nk = K >> 6;   // 128

  stage_pair(lds, pA, pB, K, K, 0, 0, 0, wA);
  stage_pair(lds, pA, pB, K, K, 0, 0, 1, wA);
  stage_pair(lds, pA, pB, K, K, 0, 0, 2, wA);
  stage_pair(lds, pA, pB, K, K, 0, 0, 3, wA);
  stage_pair(lds, pA, pB, K, K, 1, 1, 0, wA);
  stage_pair(lds, pA, pB, K, K, 1, 1, 1, wA);
  asm volatile("s_waitcnt vmcnt(4)" ::: "memory");
  __builtin_amdgcn_s_barrier();

  f32x4 acc[8][4] = {};

  for (int kt = 0; kt < nk; ++kt) {
    const int p = kt & 1;
    const u32 abase = (u32)p * 32768u;
    const u32 bbase = 65536u + (u32)p * 32768u;
    bf16x8 a0[4][2], a1[4][2], b0[2][2], b1[2][2];

    READ_A(a0, 0, abase);
    READ_B(b0, 0, bbase);
    READ_B(b1, 1, bbase);
    READ_A(a1, 1, abase);
    if (kt + 1 < nk) {
      stage_pair(lds, pA, pB, K, K, kt + 1, p ^ 1, 2, wA);
      stage_pair(lds, pA, pB, K, K, kt + 1, p ^ 1, 3, wA);
    }
    __builtin_amdgcn_sched_barrier(0);

    __builtin_amdgcn_s_setprio(1);
    MFMA_Q(0, 0, a0, b0);
    MFMA_Q(0, 1, a0, b1);
    __builtin_amdgcn_s_setprio(0);

    asm volatile("s_waitcnt lgkmcnt(0)" ::: "memory");
    __builtin_amdgcn_s_barrier();
    __builtin_amdgcn_sched_barrier(0);
    if (kt + 2 < nk) {
      stage_pair(lds, pA, pB, K, K, kt + 2, p, 0, wA);
      stage_pair(lds, pA, pB, K, K, kt + 2, p, 1, wA);
    }

    __builtin_amdgcn_s_setprio(1);
    MFMA_Q(1, 1, a1, b1);
    MFMA_Q(1, 0, a1, b0);
    __builtin_amdgcn_s_setprio(0);

    if (kt + 2 < nk) {
      asm volatile("s_waitcnt vmcnt(4)" ::: "memory");
    } else {
      asm volatile("s_waitcnt vmcnt(0)" ::: "memory");
    }
    __builtin_amdgcn_s_barrier();
  }

  // epilogue: f32 LDS-bounce (main-loop LDS dead), coalesced stores
  const int colb = (int)brow0 + wcol * 64;
  float bb[4];
#pragma unroll
  for (int n = 0; n < 4; ++n) bb[n] = bias[colb + n * 16 + l15];
  const int tr = lane >> 2, tc = (lane & 3) * 16;
  float* slotf = (float*)(void*)lds + (size_t)w * 1088;  // 16 x 68 f32
#pragma unroll
  for (int m = 0; m < 8; ++m) {
    const int rowb = (int)arow0 + wr * 128 + m * 16;
#pragma unroll
    for (int n = 0; n < 4; ++n)
#pragma unroll
      for (int r = 0; r < 4; ++r)
        slotf[(lhi * 4 + r) * 68 + n * 16 + l15] = acc[m][n][r] + bb[n];
    asm volatile("s_waitcnt lgkmcnt(0)" ::: "memory");
    float4 f0 = *(const float4*)(slotf + tr * 68 + tc);
    float4 f1 = *(const float4*)(slotf + tr * 68 + tc + 4);
    float4 f2 = *(const float4*)(slotf + tr * 68 + tc + 8);
    float4 f3 = *(const float4*)(slotf + tr * 68 + tc + 12);
    float* gp = Cout + (size_t)(rowb + tr) * N + colb + tc;
    *(float4*)gp = f0;
    *(float4*)(gp + 4) = f1;
    *(float4*)(gp + 8) = f2;
    *(float4*)(gp + 12) = f3;
    asm volatile("s_waitcnt lgkmcnt(0)" ::: "memory");
  }
}

// ---------------------------------------------------------------------------
extern "C" void kernel_launch(void* const* d_in, const int* in_sizes, int n_in,
                              void* d_out, int out_size, void* d_ws,
                              size_t ws_size, hipStream_t stream) {
  const float* x  = (const float*)d_in[0];
  // d_in[1] = Wp, d_in[2] = bp : router is identity, unused.
  const float* W1 = (const float*)d_in[3];
  const float* b1 = (const float*)d_in[4];
  const float* W2 = (const float*)d_in[5];
  const float* b2 = (const float*)d_in[6];
  float* out = (float*)d_out;

  char* ws = (char*)d_ws;
  u16* Xb  = (u16*)(ws);                       // 8192x2048 bf16 = 32 MiB
  u16* W1T = (u16*)(ws + 33554432);            // 8192x2048 bf16 = 32 MiB
  u16* W2T = (u16*)(ws + 67108864);            // 2048x8192 bf16 = 32 MiB
  u16* H   = (u16*)(ws + 100663296);           // 8192x8192 bf16 = 128 MiB

  // 1. select + convert x
  k_convert_x<<<16384, 256, 0, stream>>>(x, Xb);
  // 2. transpose-convert weights
  k_transpose_bf16<<<dim3(8192 / 64, 2048 / 64), 256, 0, stream>>>(W1, W1T, 2048, 8192);
  k_transpose_bf16<<<dim3(2048 / 64, 8192 / 64), 256, 0, stream>>>(W2, W2T, 8192, 2048);
  // 3. H = gelu(Xb @ W1 + b1) : M=8192 N=8192 K=2048, persistent 256 blocks
  k_ffn1<<<256, 512, 0, stream>>>(Xb, W1T, b1, H, 8192, 2048);
  // 4. out = H @ W2 + b2      : M=8192 N=2048 K=8192, 256 blocks, bm-chunk
  k_ffn2<<<256, 512, 0, stream>>>(H, W2T, b2, out, 2048, 8192, 8);
}